// Round 1
// baseline (749.020 us; speedup 1.0000x reference)
//
#include <hip/hip_runtime.h>
#include <hip/hip_bf16.h>
#include <math.h>

#define B_      16
#define L_      2048
#define D_MODEL 320
#define D_INNER 640
#define D_STATE 16
#define DT_RANK 20
#define H_OUT   128
#define VOCAB   65
#define N_TIS   30
#define XDBL    52   // DT_RANK + 2*D_STATE
#define TT      16   // t-tile in producer

// workspace layout (floats)
static constexpr size_t OFF_MSEQ  = 0;                         // 65*1280
static constexpr size_t OFF_MTIS  = OFF_MSEQ + VOCAB*1280;     // 30*1280
static constexpr size_t OFF_SEQN  = OFF_MTIS + N_TIS*1280;     // 65*256
static constexpr size_t OFF_TISN  = OFF_SEQN + VOCAB*256;      // 30*64 (contiguous after SEQN)
static constexpr size_t OFF_YSCAN = OFF_TISN + N_TIS*64;       // 16*640
static constexpr size_t OFF_DELTA = OFF_YSCAN + B_*D_INNER;    // 16*640*2048
static constexpr size_t OFF_DU    = OFF_DELTA + (size_t)B_*D_INNER*L_;
static constexpr size_t OFF_BBAR  = OFF_DU    + (size_t)B_*D_INNER*L_;
static constexpr size_t OFF_CBAR  = OFF_BBAR  + (size_t)B_*D_STATE*L_;

__device__ __forceinline__ float silu_f(float x) { return x / (1.0f + __expf(-x)); }

// ---------- A0: renorm embedding rows (max_norm=2) ----------
__global__ void k_renorm(const float* __restrict__ seqW, const float* __restrict__ tisW,
                         float* __restrict__ ws) {
    int v = blockIdx.x, lane = threadIdx.x;
    const float* src; float* dst; int K;
    if (v < VOCAB) { src = seqW + v*256; dst = ws + OFF_SEQN + v*256; K = 256; }
    else           { int vt = v - VOCAB; src = tisW + vt*64; dst = ws + OFF_TISN + vt*64; K = 64; }
    float ss = 0.f;
    for (int k = lane; k < K; k += 64) { float x = src[k]; ss += x*x; }
    #pragma unroll
    for (int o = 32; o; o >>= 1) ss += __shfl_xor(ss, o);
    float scale = fminf(1.0f, 2.0f / fmaxf(sqrtf(ss), 1e-12f));
    for (int k = lane; k < K; k += 64) dst[k] = src[k] * scale;
}

// ---------- A1: M_seq = seq_Wn @ inW[:, :256]^T ; M_tis = tis_n @ inW[:, 256:]^T ----------
__global__ void k_mbuild(const float* __restrict__ inW, float* __restrict__ ws) {
    int jblk = blockIdx.x * 128;
    const float* seqn = ws + OFF_SEQN;
    const float* tisn = ws + OFF_TISN;
    for (int o = threadIdx.x; o < (VOCAB + N_TIS) * 128; o += 256) {
        int v = o >> 7, jj = o & 127, j = jblk + jj;
        float acc = 0.f;
        if (v < VOCAB) {
            const float* a = seqn + v*256; const float* w = inW + j*320;
            #pragma unroll 8
            for (int k = 0; k < 256; ++k) acc += a[k]*w[k];
            ws[OFF_MSEQ + (size_t)v*1280 + j] = acc;
        } else {
            int vt = v - VOCAB;
            const float* a = tisn + vt*64; const float* w = inW + j*320 + 256;
            #pragma unroll 8
            for (int k = 0; k < 64; ++k) acc += a[k]*w[k];
            ws[OFF_MTIS + (size_t)vt*1280 + j] = acc;
        }
    }
}

// ---------- K2: fused conv+silu -> x_proj -> dt_proj+softplus; writes delta, delta*u ([b,d,t]), Bbar, Cbar ----------
__global__ __launch_bounds__(256) void k_produce(
    const int* __restrict__ idx, const int* __restrict__ tissue_id,
    const int* __restrict__ seq_lengths,
    const float* __restrict__ conv_w, const float* __restrict__ conv_b,
    const float* __restrict__ xW, const float* __restrict__ dtW,
    const float* __restrict__ dtb, float* __restrict__ ws)
{
    __shared__ float u_l[TT*641];     // stride 641 to break bank conflicts
    __shared__ float xd_l[TT*53];
    __shared__ int   idx_l[TT+3];
    int b = blockIdx.y;
    int t0 = blockIdx.x * TT;
    int t_last = seq_lengths[b] - 1;
    if (t0 > t_last) return;          // scan never reads beyond t_last
    int tid = threadIdx.x;
    const float* Mseq = ws + OFF_MSEQ;
    const float* Mtis = ws + OFF_MTIS;
    int tis = tissue_id[b];
    if (tid < TT+3) {
        int t = t0 - 3 + tid;
        idx_l[tid] = (t >= 0) ? idx[b*L_ + t] : 0;
    }
    __syncthreads();

    // phase 1: u = silu(causal depthwise conv4 of xz[:, :640])
    for (int d = tid; d < D_INNER; d += 256) {
        float w0 = conv_w[d*4+0], w1 = conv_w[d*4+1], w2 = conv_w[d*4+2], w3 = conv_w[d*4+3];
        float cb = conv_b[d];
        float mt = Mtis[(size_t)tis*1280 + d];
        auto XZ = [&](int k) -> float {
            int row = idx_l[k];
            return row ? (Mseq[(size_t)row*1280 + d] + mt) : 0.0f;
        };
        float a0 = XZ(0), a1 = XZ(1), a2 = XZ(2);
        for (int t = 0; t < TT; ++t) {
            float a3 = XZ(t+3);
            float c = w0*a0 + w1*a1 + w2*a2 + w3*a3 + cb;
            u_l[t*641 + d] = silu_f(c);
            a0 = a1; a1 = a2; a2 = a3;
        }
    }
    __syncthreads();

    // phase 2: x_dbl[t][r] = sum_d u[t][d]*xW[r][d]   (16 threads split d per t, shfl reduce)
    {
        int g = tid >> 4;        // t
        int j = tid & 15;        // d-slice
        int d0 = j * 40;
        float ur[40];
        #pragma unroll
        for (int i = 0; i < 40; ++i) ur[i] = u_l[g*641 + d0 + i];
        for (int r = 0; r < XDBL; ++r) {
            const float* wrow = xW + r*D_INNER + d0;
            float acc = 0.f;
            #pragma unroll
            for (int i = 0; i < 40; i += 4) {
                float4 w4 = *(const float4*)(wrow + i);
                acc += ur[i]*w4.x + ur[i+1]*w4.y + ur[i+2]*w4.z + ur[i+3]*w4.w;
            }
            acc += __shfl_xor(acc, 1); acc += __shfl_xor(acc, 2);
            acc += __shfl_xor(acc, 4); acc += __shfl_xor(acc, 8);
            if (j == 0) xd_l[g*53 + r] = acc;
        }
    }
    __syncthreads();

    // phase 3: delta = softplus(dt @ dtW^T + b); write delta, delta*u transposed [b,d,t]; Bbar/Cbar [b,s,t]
    float* delta_g = ws + OFF_DELTA + (size_t)b*D_INNER*L_;
    float* du_g    = ws + OFF_DU    + (size_t)b*D_INNER*L_;
    for (int d = tid; d < D_INNER; d += 256) {
        float wr[20];
        #pragma unroll
        for (int i = 0; i < 20; i += 4) {
            float4 w4 = *(const float4*)(dtW + d*20 + i);
            wr[i] = w4.x; wr[i+1] = w4.y; wr[i+2] = w4.z; wr[i+3] = w4.w;
        }
        float bd = dtb[d];
        float* dp = delta_g + (size_t)d*L_ + t0;
        float* up = du_g    + (size_t)d*L_ + t0;
        for (int t = 0; t < TT; ++t) {
            float x = bd;
            #pragma unroll
            for (int r = 0; r < 20; ++r) x += xd_l[t*53 + r] * wr[r];
            float sp = fmaxf(x, 0.0f) + log1pf(__expf(-fabsf(x)));   // stable softplus
            dp[t] = sp;
            up[t] = sp * u_l[t*641 + d];
        }
    }
    {
        int s = tid >> 4, t = tid & 15;
        ws[OFF_BBAR + ((size_t)b*D_STATE + s)*L_ + t0 + t] = xd_l[t*53 + DT_RANK + s];
        ws[OFF_CBAR + ((size_t)b*D_STATE + s)*L_ + t0 + t] = xd_l[t*53 + DT_RANK + D_STATE + s];
    }
}

// ---------- K4: selective scan; thread = (d,s) channel; emit y at t_last only ----------
__global__ __launch_bounds__(256) void k_scan(const int* __restrict__ seq_lengths,
                                              const float* __restrict__ A_log,
                                              float* __restrict__ ws)
{
    __shared__ float dl_l[16*68], du_l[16*68], Bb_l[16*68];   // stride 68: 2-way max conflict
    int b = blockIdx.y, dg = blockIdx.x;
    int tid = threadIdx.x;
    int dl = tid >> 4, s = tid & 15;
    int d = dg*16 + dl;
    float A = -__expf(A_log[d*D_STATE + s]);
    int t_last = seq_lengths[b] - 1;
    // cooperative-load mapping: row = tid>>4, 4 cols per thread
    int lr = tid >> 4, lc = (tid & 15) * 4;
    const float* dR = ws + OFF_DELTA + ((size_t)b*D_INNER + dg*16 + lr)*L_;
    const float* uR = ws + OFF_DU    + ((size_t)b*D_INNER + dg*16 + lr)*L_;
    const float* bR = ws + OFF_BBAR  + ((size_t)b*D_STATE + lr)*L_;
    float h = 0.0f;
    for (int t0 = 0; t0 <= t_last; t0 += 64) {
        *(float4*)(dl_l + lr*68 + lc) = *(const float4*)(dR + t0 + lc);
        *(float4*)(du_l + lr*68 + lc) = *(const float4*)(uR + t0 + lc);
        *(float4*)(Bb_l + lr*68 + lc) = *(const float4*)(bR + t0 + lc);
        __syncthreads();
        int tend = min(63, t_last - t0);
        for (int tt = 0; tt <= tend; ++tt) {
            float dlt = dl_l[dl*68 + tt];
            float dA  = __expf(dlt * A);
            float dbu = du_l[dl*68 + tt] * Bb_l[s*68 + tt];
            h = fmaf(dA, h, dbu);
        }
        __syncthreads();
    }
    float c = ws[OFF_CBAR + ((size_t)b*D_STATE + s)*L_ + t_last];
    float v = h * c;
    v += __shfl_xor(v, 1); v += __shfl_xor(v, 2);
    v += __shfl_xor(v, 4); v += __shfl_xor(v, 8);
    if (s == 0) ws[OFF_YSCAN + (size_t)b*D_INNER + d] = v;
}

// ---------- K5: per-batch epilogue: skip + gate + out_proj + MLP head ----------
__global__ __launch_bounds__(320) void k_final(
    const int* __restrict__ idx, const int* __restrict__ tissue_id,
    const int* __restrict__ seq_lengths,
    const float* __restrict__ conv_w, const float* __restrict__ conv_b,
    const float* __restrict__ Dskip, const float* __restrict__ outW,
    const float* __restrict__ p1W, const float* __restrict__ p1b,
    const float* __restrict__ p2W, const float* __restrict__ p2b,
    const float* __restrict__ ws, float* __restrict__ out)
{
    __shared__ float y_l[D_INNER];
    __shared__ float o_l[D_MODEL];
    __shared__ float h1_l[H_OUT];
    int b = blockIdx.x, tid = threadIdx.x;
    int t_last = seq_lengths[b] - 1;
    int tis = tissue_id[b];
    const float* Mseq = ws + OFF_MSEQ;
    const float* Mtis = ws + OFF_MTIS;
    int rows[4];
    #pragma unroll
    for (int k = 0; k < 4; ++k) {
        int t = t_last - 3 + k;
        rows[k] = (t >= 0) ? idx[b*L_ + t] : 0;
    }
    for (int d = tid; d < D_INNER; d += 320) {
        float conv = conv_b[d];
        const float* cw = conv_w + d*4;
        #pragma unroll
        for (int k = 0; k < 4; ++k) {
            int row = rows[k];
            float xz = row ? (Mseq[(size_t)row*1280 + d] + Mtis[(size_t)tis*1280 + d]) : 0.0f;
            conv += cw[k] * xz;
        }
        float u = silu_f(conv);
        int rowL = rows[3];
        float z = rowL ? (Mseq[(size_t)rowL*1280 + 640 + d] + Mtis[(size_t)tis*1280 + 640 + d]) : 0.0f;
        float ys = ws[OFF_YSCAN + (size_t)b*D_INNER + d];
        y_l[d] = (ys + u * Dskip[d]) * silu_f(z);
    }
    __syncthreads();
    if (tid < D_MODEL) {
        const float* w = outW + tid*D_INNER;
        float acc = 0.f;
        #pragma unroll 4
        for (int k = 0; k < D_INNER; k += 4) {
            float4 w4 = *(const float4*)(w + k);
            acc += y_l[k]*w4.x + y_l[k+1]*w4.y + y_l[k+2]*w4.z + y_l[k+3]*w4.w;
        }
        o_l[tid] = acc;
    }
    __syncthreads();
    if (tid < H_OUT) {
        const float* w = p1W + tid*D_MODEL;
        float acc = p1b[tid];
        #pragma unroll 4
        for (int k = 0; k < D_MODEL; k += 4) {
            float4 w4 = *(const float4*)(w + k);
            acc += o_l[k]*w4.x + o_l[k+1]*w4.y + o_l[k+2]*w4.z + o_l[k+3]*w4.w;
        }
        h1_l[tid] = fmaxf(acc, 0.0f);
    }
    __syncthreads();
    if (tid == 0) {
        float acc = p2b[0];
        for (int k = 0; k < H_OUT; ++k) acc += h1_l[k]*p2W[k];
        out[b] = acc;
    }
}

extern "C" void kernel_launch(void* const* d_in, const int* in_sizes, int n_in,
                              void* d_out, int out_size, void* d_ws, size_t ws_size,
                              hipStream_t stream)
{
    const int*   idx   = (const int*)d_in[0];
    const int*   tis   = (const int*)d_in[1];
    const int*   slen  = (const int*)d_in[2];
    const float* seqW  = (const float*)d_in[3];
    const float* tisW  = (const float*)d_in[4];
    const float* inW   = (const float*)d_in[5];
    const float* convw = (const float*)d_in[6];
    const float* convb = (const float*)d_in[7];
    const float* xW    = (const float*)d_in[8];
    const float* dtW   = (const float*)d_in[9];
    const float* dtb   = (const float*)d_in[10];
    const float* Alog  = (const float*)d_in[11];
    const float* Dsk   = (const float*)d_in[12];
    const float* outW  = (const float*)d_in[13];
    const float* p1W   = (const float*)d_in[14];
    const float* p1b   = (const float*)d_in[15];
    const float* p2W   = (const float*)d_in[16];
    const float* p2b   = (const float*)d_in[17];
    float* ws  = (float*)d_ws;
    float* out = (float*)d_out;

    hipLaunchKernelGGL(k_renorm,  dim3(VOCAB + N_TIS), dim3(64),  0, stream, seqW, tisW, ws);
    hipLaunchKernelGGL(k_mbuild,  dim3(10),            dim3(256), 0, stream, inW, ws);
    hipLaunchKernelGGL(k_produce, dim3(L_/TT, B_),     dim3(256), 0, stream,
                       idx, tis, slen, convw, convb, xW, dtW, dtb, ws);
    hipLaunchKernelGGL(k_scan,    dim3(D_INNER/16, B_),dim3(256), 0, stream, slen, Alog, ws);
    hipLaunchKernelGGL(k_final,   dim3(B_),            dim3(320), 0, stream,
                       idx, tis, slen, convw, convb, Dsk, outW, p1W, p1b, p2W, p2b, ws, out);
}

// Round 2
// 426.146 us; speedup vs baseline: 1.7577x; 1.7577x over previous
//
#include <hip/hip_runtime.h>
#include <hip/hip_bf16.h>
#include <math.h>

#define B_      16
#define L_      2048
#define D_MODEL 320
#define D_INNER 640
#define D_STATE 16
#define DT_RANK 20
#define H_OUT   128
#define VOCAB   65
#define N_TIS   30
#define XDBL    52   // DT_RANK + 2*D_STATE
#define TT      16   // t-tile in producer

// workspace layout (floats)
static constexpr size_t OFF_MSEQ  = 0;                         // 65*1280
static constexpr size_t OFF_MTIS  = OFF_MSEQ + VOCAB*1280;     // 30*1280
static constexpr size_t OFF_YSCAN = OFF_MTIS + N_TIS*1280;     // 16*640
static constexpr size_t OFF_DELTA = OFF_YSCAN + B_*D_INNER;    // 16*640*2048
static constexpr size_t OFF_DU    = OFF_DELTA + (size_t)B_*D_INNER*L_;
static constexpr size_t OFF_BBAR  = OFF_DU    + (size_t)B_*D_INNER*L_;
static constexpr size_t OFF_CBAR  = OFF_BBAR  + (size_t)B_*D_STATE*L_;

__device__ __forceinline__ float silu_f(float x) { return x / (1.0f + __expf(-x)); }

// ---------- A0+A1 fused: renorm embedding row (max_norm=2) then M-row = row @ inW-slice^T ----------
// grid (VOCAB+N_TIS, 5), block 256. One output element per thread.
__global__ __launch_bounds__(256) void k_mbuild(
    const float* __restrict__ seqW, const float* __restrict__ tisW,
    const float* __restrict__ inW, float* __restrict__ ws)
{
    __shared__ float a_l[256];
    __shared__ float red[4];
    int v = blockIdx.x, tid = threadIdx.x;
    int K, wofs; const float* src; float* dstM;
    if (v < VOCAB) { K = 256; wofs = 0;   src = seqW + (size_t)v*256;        dstM = ws + OFF_MSEQ + (size_t)v*1280; }
    else           { K = 64;  wofs = 256; src = tisW + (size_t)(v-VOCAB)*64; dstM = ws + OFF_MTIS + (size_t)(v-VOCAB)*1280; }
    float x = (tid < K) ? src[tid] : 0.0f;
    float ss = x * x;
    #pragma unroll
    for (int o = 32; o; o >>= 1) ss += __shfl_xor(ss, o);
    if ((tid & 63) == 0) red[tid >> 6] = ss;
    __syncthreads();
    float tot = red[0] + red[1] + red[2] + red[3];
    float scale = fminf(1.0f, 2.0f / fmaxf(sqrtf(tot), 1e-12f));
    if (tid < K) a_l[tid] = x * scale;
    __syncthreads();

    int j = blockIdx.y * 256 + tid;   // 5*256=1280 columns
    const float* w = inW + (size_t)j*320 + wofs;
    float ac0 = 0.f, ac1 = 0.f, ac2 = 0.f, ac3 = 0.f;
    #pragma unroll 4
    for (int k = 0; k < K; k += 4) {
        float4 w4 = *(const float4*)(w + k);
        ac0 += a_l[k+0]*w4.x; ac1 += a_l[k+1]*w4.y;
        ac2 += a_l[k+2]*w4.z; ac3 += a_l[k+3]*w4.w;
    }
    dstM[j] = (ac0 + ac1) + (ac2 + ac3);
}

// ---------- K2: fused conv+silu -> x_proj -> dt_proj+softplus; writes delta, delta*u ([b,d,t]), Bbar, Cbar ----------
__global__ __launch_bounds__(256) void k_produce(
    const int* __restrict__ idx, const int* __restrict__ tissue_id,
    const int* __restrict__ seq_lengths,
    const float* __restrict__ conv_w, const float* __restrict__ conv_b,
    const float* __restrict__ xW, const float* __restrict__ dtW,
    const float* __restrict__ dtb, float* __restrict__ ws)
{
    __shared__ float u_l[TT*641];     // stride 641 to break bank conflicts
    __shared__ float xd_l[TT*53];
    __shared__ int   idx_l[TT+3];
    int b = blockIdx.y;
    int t0 = blockIdx.x * TT;
    int t_last = seq_lengths[b] - 1;
    if (t0 > t_last) return;          // scan never reads beyond t_last
    int tid = threadIdx.x;
    const float* Mseq = ws + OFF_MSEQ;
    const float* Mtis = ws + OFF_MTIS;
    int tis = tissue_id[b];
    if (tid < TT+3) {
        int t = t0 - 3 + tid;
        idx_l[tid] = (t >= 0) ? idx[b*L_ + t] : 0;
    }
    __syncthreads();

    // phase 1: u = silu(causal depthwise conv4 of xz[:, :640])
    for (int d = tid; d < D_INNER; d += 256) {
        float w0 = conv_w[d*4+0], w1 = conv_w[d*4+1], w2 = conv_w[d*4+2], w3 = conv_w[d*4+3];
        float cb = conv_b[d];
        float mt = Mtis[(size_t)tis*1280 + d];
        auto XZ = [&](int k) -> float {
            int row = idx_l[k];
            return row ? (Mseq[(size_t)row*1280 + d] + mt) : 0.0f;
        };
        float a0 = XZ(0), a1 = XZ(1), a2 = XZ(2);
        for (int t = 0; t < TT; ++t) {
            float a3 = XZ(t+3);
            float c = w0*a0 + w1*a1 + w2*a2 + w3*a3 + cb;
            u_l[t*641 + d] = silu_f(c);
            a0 = a1; a1 = a2; a2 = a3;
        }
    }
    __syncthreads();

    // phase 2: x_dbl[t][r] = sum_d u[t][d]*xW[r][d]   (16 threads split d per t, shfl reduce)
    {
        int g = tid >> 4;        // t
        int j = tid & 15;        // d-slice
        int d0 = j * 40;
        float ur[40];
        #pragma unroll
        for (int i = 0; i < 40; ++i) ur[i] = u_l[g*641 + d0 + i];
        for (int r = 0; r < XDBL; ++r) {
            const float* wrow = xW + r*D_INNER + d0;
            float acc = 0.f;
            #pragma unroll
            for (int i = 0; i < 40; i += 4) {
                float4 w4 = *(const float4*)(wrow + i);
                acc += ur[i]*w4.x + ur[i+1]*w4.y + ur[i+2]*w4.z + ur[i+3]*w4.w;
            }
            acc += __shfl_xor(acc, 1); acc += __shfl_xor(acc, 2);
            acc += __shfl_xor(acc, 4); acc += __shfl_xor(acc, 8);
            if (j == 0) xd_l[g*53 + r] = acc;
        }
    }
    __syncthreads();

    // phase 3: delta = softplus(dt @ dtW^T + b); write delta, delta*u transposed [b,d,t]; Bbar/Cbar [b,s,t]
    float* delta_g = ws + OFF_DELTA + (size_t)b*D_INNER*L_;
    float* du_g    = ws + OFF_DU    + (size_t)b*D_INNER*L_;
    for (int d = tid; d < D_INNER; d += 256) {
        float wr[20];
        #pragma unroll
        for (int i = 0; i < 20; i += 4) {
            float4 w4 = *(const float4*)(dtW + d*20 + i);
            wr[i] = w4.x; wr[i+1] = w4.y; wr[i+2] = w4.z; wr[i+3] = w4.w;
        }
        float bd = dtb[d];
        float* dp = delta_g + (size_t)d*L_ + t0;
        float* up = du_g    + (size_t)d*L_ + t0;
        for (int t = 0; t < TT; ++t) {
            float x = bd;
            #pragma unroll
            for (int r = 0; r < 20; ++r) x += xd_l[t*53 + r] * wr[r];
            float sp = fmaxf(x, 0.0f) + log1pf(__expf(-fabsf(x)));   // stable softplus
            dp[t] = sp;
            up[t] = sp * u_l[t*641 + d];
        }
    }
    {
        int s = tid >> 4, t = tid & 15;
        ws[OFF_BBAR + ((size_t)b*D_STATE + s)*L_ + t0 + t] = xd_l[t*53 + DT_RANK + s];
        ws[OFF_CBAR + ((size_t)b*D_STATE + s)*L_ + t0 + t] = xd_l[t*53 + DT_RANK + D_STATE + s];
    }
}

// ---------- K4: selective scan; thread = (d,s) channel; emit y at t_last only ----------
__global__ __launch_bounds__(256) void k_scan(const int* __restrict__ seq_lengths,
                                              const float* __restrict__ A_log,
                                              float* __restrict__ ws)
{
    __shared__ float dl_l[16*68], du_l[16*68], Bb_l[16*68];   // stride 68: 2-way max conflict
    int b = blockIdx.y, dg = blockIdx.x;
    int tid = threadIdx.x;
    int dl = tid >> 4, s = tid & 15;
    int d = dg*16 + dl;
    float A = -__expf(A_log[d*D_STATE + s]);
    int t_last = seq_lengths[b] - 1;
    // cooperative-load mapping: row = tid>>4, 4 cols per thread
    int lr = tid >> 4, lc = (tid & 15) * 4;
    const float* dR = ws + OFF_DELTA + ((size_t)b*D_INNER + dg*16 + lr)*L_;
    const float* uR = ws + OFF_DU    + ((size_t)b*D_INNER + dg*16 + lr)*L_;
    const float* bR = ws + OFF_BBAR  + ((size_t)b*D_STATE + lr)*L_;
    float h = 0.0f;
    for (int t0 = 0; t0 <= t_last; t0 += 64) {
        *(float4*)(dl_l + lr*68 + lc) = *(const float4*)(dR + t0 + lc);
        *(float4*)(du_l + lr*68 + lc) = *(const float4*)(uR + t0 + lc);
        *(float4*)(Bb_l + lr*68 + lc) = *(const float4*)(bR + t0 + lc);
        __syncthreads();
        int tend = min(63, t_last - t0);
        for (int tt = 0; tt <= tend; ++tt) {
            float dlt = dl_l[dl*68 + tt];
            float dA  = __expf(dlt * A);
            float dbu = du_l[dl*68 + tt] * Bb_l[s*68 + tt];
            h = fmaf(dA, h, dbu);
        }
        __syncthreads();
    }
    float c = ws[OFF_CBAR + ((size_t)b*D_STATE + s)*L_ + t_last];
    float v = h * c;
    v += __shfl_xor(v, 1); v += __shfl_xor(v, 2);
    v += __shfl_xor(v, 4); v += __shfl_xor(v, 8);
    if (s == 0) ws[OFF_YSCAN + (size_t)b*D_INNER + d] = v;
}

// ---------- K5: per-batch epilogue: skip + gate + out_proj + MLP head ----------
__global__ __launch_bounds__(320) void k_final(
    const int* __restrict__ idx, const int* __restrict__ tissue_id,
    const int* __restrict__ seq_lengths,
    const float* __restrict__ conv_w, const float* __restrict__ conv_b,
    const float* __restrict__ Dskip, const float* __restrict__ outW,
    const float* __restrict__ p1W, const float* __restrict__ p1b,
    const float* __restrict__ p2W, const float* __restrict__ p2b,
    const float* __restrict__ ws, float* __restrict__ out)
{
    __shared__ float y_l[D_INNER];
    __shared__ float o_l[D_MODEL];
    __shared__ float h1_l[H_OUT];
    int b = blockIdx.x, tid = threadIdx.x;
    int t_last = seq_lengths[b] - 1;
    int tis = tissue_id[b];
    const float* Mseq = ws + OFF_MSEQ;
    const float* Mtis = ws + OFF_MTIS;
    int rows[4];
    #pragma unroll
    for (int k = 0; k < 4; ++k) {
        int t = t_last - 3 + k;
        rows[k] = (t >= 0) ? idx[b*L_ + t] : 0;
    }
    for (int d = tid; d < D_INNER; d += 320) {
        float conv = conv_b[d];
        const float* cw = conv_w + d*4;
        #pragma unroll
        for (int k = 0; k < 4; ++k) {
            int row = rows[k];
            float xz = row ? (Mseq[(size_t)row*1280 + d] + Mtis[(size_t)tis*1280 + d]) : 0.0f;
            conv += cw[k] * xz;
        }
        float u = silu_f(conv);
        int rowL = rows[3];
        float z = rowL ? (Mseq[(size_t)rowL*1280 + 640 + d] + Mtis[(size_t)tis*1280 + 640 + d]) : 0.0f;
        float ys = ws[OFF_YSCAN + (size_t)b*D_INNER + d];
        y_l[d] = (ys + u * Dskip[d]) * silu_f(z);
    }
    __syncthreads();
    if (tid < D_MODEL) {
        const float* w = outW + tid*D_INNER;
        float acc = 0.f;
        #pragma unroll 4
        for (int k = 0; k < D_INNER; k += 4) {
            float4 w4 = *(const float4*)(w + k);
            acc += y_l[k]*w4.x + y_l[k+1]*w4.y + y_l[k+2]*w4.z + y_l[k+3]*w4.w;
        }
        o_l[tid] = acc;
    }
    __syncthreads();
    if (tid < H_OUT) {
        const float* w = p1W + tid*D_MODEL;
        float acc = p1b[tid];
        #pragma unroll 4
        for (int k = 0; k < D_MODEL; k += 4) {
            float4 w4 = *(const float4*)(w + k);
            acc += o_l[k]*w4.x + o_l[k+1]*w4.y + o_l[k+2]*w4.z + o_l[k+3]*w4.w;
        }
        h1_l[tid] = fmaxf(acc, 0.0f);
    }
    __syncthreads();
    if (tid == 0) {
        float acc = p2b[0];
        for (int k = 0; k < H_OUT; ++k) acc += h1_l[k]*p2W[k];
        out[b] = acc;
    }
}

extern "C" void kernel_launch(void* const* d_in, const int* in_sizes, int n_in,
                              void* d_out, int out_size, void* d_ws, size_t ws_size,
                              hipStream_t stream)
{
    const int*   idx   = (const int*)d_in[0];
    const int*   tis   = (const int*)d_in[1];
    const int*   slen  = (const int*)d_in[2];
    const float* seqW  = (const float*)d_in[3];
    const float* tisW  = (const float*)d_in[4];
    const float* inW   = (const float*)d_in[5];
    const float* convw = (const float*)d_in[6];
    const float* convb = (const float*)d_in[7];
    const float* xW    = (const float*)d_in[8];
    const float* dtW   = (const float*)d_in[9];
    const float* dtb   = (const float*)d_in[10];
    const float* Alog  = (const float*)d_in[11];
    const float* Dsk   = (const float*)d_in[12];
    const float* outW  = (const float*)d_in[13];
    const float* p1W   = (const float*)d_in[14];
    const float* p1b   = (const float*)d_in[15];
    const float* p2W   = (const float*)d_in[16];
    const float* p2b   = (const float*)d_in[17];
    float* ws  = (float*)d_ws;
    float* out = (float*)d_out;

    hipLaunchKernelGGL(k_mbuild,  dim3(VOCAB + N_TIS, 5), dim3(256), 0, stream, seqW, tisW, inW, ws);
    hipLaunchKernelGGL(k_produce, dim3(L_/TT, B_),        dim3(256), 0, stream,
                       idx, tis, slen, convw, convb, xW, dtW, dtb, ws);
    hipLaunchKernelGGL(k_scan,    dim3(D_INNER/16, B_),   dim3(256), 0, stream, slen, Alog, ws);
    hipLaunchKernelGGL(k_final,   dim3(B_),               dim3(320), 0, stream,
                       idx, tis, slen, convw, convb, Dsk, outW, p1W, p1b, p2W, p2b, ws, out);
}